// Round 1
// 1031.675 us; speedup vs baseline: 1.2009x; 1.2009x over previous
//
#include <hip/hip_runtime.h>

// GPT-J attention, B=2 S=2048 HIDDEN=4096 H=16 D=256 ROTARY=64.
// Pipeline: cvt(hs)->bf16 | W^T->bf16 | QKV GEMM | RoPE(Q,K) | V^T | flash attn
//           | out proj -> f32.
// R2: flash rewritten — 16 q-rows/wave, BQ=64, LDS 72KB.
// R3: fix k_vtrans typo.
// R4: GEMM rewritten to 256x256 8-phase pipeline (m201 structure):
//     BK=64, 8 waves (2Mx4N), 128KB LDS dbuf, st_16x32 swizzle, raw s_barrier
//     (no __syncthreads -> no vmcnt(0) drain), counted vmcnt(4), setprio(1) on MFMA.

typedef unsigned short u16;
typedef __attribute__((ext_vector_type(4))) float f32x4;
typedef __attribute__((ext_vector_type(8))) short s16x8;
typedef __attribute__((ext_vector_type(4))) unsigned short u16x4;

#define HID 4096
#define SEQ 2048
#define NMAT (4096ull * 4096ull)

__device__ __forceinline__ u16 f2bf(float x) {
  unsigned int u = __builtin_bit_cast(unsigned int, x);
  u += 0x7FFFu + ((u >> 16) & 1u);   // RNE
  return (u16)(u >> 16);
}
__device__ __forceinline__ float bf2f(u16 x) {
  unsigned int u = ((unsigned int)x) << 16;
  return __builtin_bit_cast(float, u);
}
// async global->LDS, 16B/lane. LDS dest is wave-uniform base + lane*16.
__device__ __forceinline__ void cp16(const void* g, void* l) {
  __builtin_amdgcn_global_load_lds((__attribute__((address_space(1))) void*)(g),
                                   (__attribute__((address_space(3))) void*)(l),
                                   16, 0, 0);
}

// ---------------- fp32 -> bf16 convert (contiguous) ----------------
__global__ __launch_bounds__(256) void k_cvt(const float* __restrict__ src,
                                             u16* __restrict__ dst) {
  size_t i = ((size_t)blockIdx.x * 256 + threadIdx.x) * 8;
  f32x4 a = *(const f32x4*)(src + i);
  f32x4 b = *(const f32x4*)(src + i + 4);
  u16x4 o0, o1;
  o0[0] = f2bf(a[0]); o0[1] = f2bf(a[1]); o0[2] = f2bf(a[2]); o0[3] = f2bf(a[3]);
  o1[0] = f2bf(b[0]); o1[1] = f2bf(b[1]); o1[2] = f2bf(b[2]); o1[3] = f2bf(b[3]);
  *(u16x4*)(dst + i) = o0;
  *(u16x4*)(dst + i + 4) = o1;
}

// ---------------- W [K,N] fp32 -> WT [N,K] bf16 ----------------
__global__ __launch_bounds__(256) void k_wtrans(const float* __restrict__ W0,
                                                const float* __restrict__ W1,
                                                const float* __restrict__ W2,
                                                const float* __restrict__ W3,
                                                u16* __restrict__ WT) {
  int z = blockIdx.z;
  const float* W = (z == 0) ? W0 : (z == 1) ? W1 : (z == 2) ? W2 : W3;
  u16* T = WT + (size_t)z * NMAT;
  __shared__ u16 tile[64][70];
  int t = threadIdx.x, tx = t & 15, ty = t >> 4;
  int n0 = blockIdx.x * 64, k0 = blockIdx.y * 64;
  for (int i = 0; i < 4; i++) {
    int kl = ty + 16 * i;
    f32x4 v = *(const f32x4*)(W + (size_t)(k0 + kl) * HID + n0 + tx * 4);
    tile[kl][tx * 4 + 0] = f2bf(v[0]);
    tile[kl][tx * 4 + 1] = f2bf(v[1]);
    tile[kl][tx * 4 + 2] = f2bf(v[2]);
    tile[kl][tx * 4 + 3] = f2bf(v[3]);
  }
  __syncthreads();
  for (int i = 0; i < 4; i++) {
    int nl = ty + 16 * i;
    u16x4 o;
    o[0] = tile[tx * 4 + 0][nl];
    o[1] = tile[tx * 4 + 1][nl];
    o[2] = tile[tx * 4 + 2][nl];
    o[3] = tile[tx * 4 + 3][nl];
    *(u16x4*)(T + (size_t)(n0 + nl) * HID + k0 + tx * 4) = o;
  }
}

// ---------------- V [tok][h*256+d] -> Vt [b][h][d][tok] (bf16) ----------------
__global__ __launch_bounds__(256) void k_vtrans(const u16* __restrict__ V,
                                                u16* __restrict__ Vt) {
  int bh = blockIdx.z, b = bh >> 4, h = bh & 15;
  int tok0 = blockIdx.x * 64, d0 = blockIdx.y * 64;
  __shared__ u16 tile[64][70];
  int t = threadIdx.x, tx = t & 15, ty = t >> 4;
  for (int i = 0; i < 4; i++) {
    int tl = ty + 16 * i;
    u16x4 v = *(const u16x4*)(V + (size_t)(b * SEQ + tok0 + tl) * HID + h * 256 + d0 + tx * 4);
    tile[tl][tx * 4 + 0] = v[0];
    tile[tl][tx * 4 + 1] = v[1];
    tile[tl][tx * 4 + 2] = v[2];
    tile[tl][tx * 4 + 3] = v[3];
  }
  __syncthreads();
  for (int i = 0; i < 4; i++) {
    int dl = ty + 16 * i;
    u16x4 o;
    o[0] = tile[tx * 4 + 0][dl];
    o[1] = tile[tx * 4 + 1][dl];
    o[2] = tile[tx * 4 + 2][dl];
    o[3] = tile[tx * 4 + 3][dl];
    *(u16x4*)(Vt + ((size_t)bh * 256 + d0 + dl) * SEQ + tok0 + tx * 4) = o;
  }
}

// ---------------- GEMM 256x256 tile, 8-phase pipeline (m201 structure) ----------------
// C[M,N] = A[M,K] * Bt[N,K]^T.  BM=BN=256, BK=64, 512 thr = 8 waves (2M x 4N).
// LDS 128KB: [buf 2][mat A/B][half 2] x 16KB; half-buf layout [ks 2][row 128][col 32] bf16
// with byte swizzle f(x) = x ^ (((x>>9)&1)<<5)  (st_16x32; involution).
// Staging: linear global_load_lds dest + inverse-swizzled global source (rule #21).
// Per 2 K-tiles: 8 phases of {ds_read quadrant | stage 1 half-tile | s_barrier |
// lgkmcnt(0) | setprio(1) 16xMFMA setprio(0) | [vmcnt(4) at ph4/8] | s_barrier}.
// Stage->read safety: every staged region's last ds_read completed >=1 barrier earlier
// (read schedule 12/4/8/0); vmcnt(4) leaves exactly the 2 not-yet-needed half-tiles in flight.
template <bool QKV>
__global__ __launch_bounds__(512, 2) void k_gemm8(const u16* __restrict__ A,
                                                  const u16* __restrict__ Bt0,
                                                  u16* __restrict__ Cb0,
                                                  float* __restrict__ Cf) {
  __shared__ u16 lds[65536];   // 128 KB
  char* lds8 = (char*)lds;
  const int t = threadIdx.x, lane = t & 63, w = t >> 6;
  const int wm = w >> 2, wn = w & 3;
  const int l15 = lane & 15, g = lane >> 4;
  int lin = blockIdx.y * 16 + blockIdx.x;
  int swz = (lin & 7) * 32 + (lin >> 3);   // XCD-contiguous tile chunks (256 % 8 == 0)
  const int bm = (swz >> 4) * 256, bn = (swz & 15) * 256;
  const u16* Bt = Bt0;
  u16* Cb = Cb0;
  float scale = 1.f;
  if (QKV) {
    int z = blockIdx.z;
    Bt += (size_t)z * NMAT;
    Cb += (size_t)z * NMAT;
    if (z == 0) scale = 0.0625f;   // q / sqrt(256), commutes with RoPE
  }
  // staging coords: thread t writes LDS linear L = j*8192 + t*16 of a half-buf;
  // source element = logical coords of P = L ^ (((L>>9)&1)<<5)
  const int Px = (t * 16) ^ (((t >> 5) & 1) << 5);
  const int r_s = Px >> 6, c_s = (Px & 63) >> 1;
  const u16* gA0 = A + (size_t)(bm + r_s) * HID + c_s;
  const u16* gA1 = gA0 + 128ull * HID;
  const u16* gB0 = Bt + (size_t)(bn + r_s) * HID + c_s;
  const u16* gB1 = gB0 + 128ull * HID;
  char* stA = lds8 + w * 1024;            // + buf(0/65536) + half*16384 (+8192 for j=1)
  char* stB = lds8 + 32768 + w * 1024;
  // ds-read base byte offsets (buf0); +65536 for buf1. swizzle bit from row = ... + l15.
  const int sb = ((l15 >> 3) & 1) << 5;
  const int aL0 = wm * 16384 + ((l15 * 64 + g * 16) ^ sb);
  const int bL0 = 32768 + (wn >> 1) * 16384 + ((((wn & 1) * 64 + l15) * 64 + g * 16) ^ sb);
  const int aL1 = aL0 + 65536, bL1 = bL0 + 65536;

  f32x4 acc[8][4] = {};
  s16x8 af[4][2], b0[2][2], b1[2][2];

#define STG(P, D, KT) { const u16* s_ = (P) + (size_t)(KT) * 64; \
                        cp16(s_, (D)); cp16(s_ + 32, (D) + 8192); }
#define LDA8(MH, AL) \
  _Pragma("unroll") for (int mi = 0; mi < 4; mi++) { \
    af[mi][0] = *(const s16x8*)(lds8 + (AL) + (MH) * 4096 + mi * 1024); \
    af[mi][1] = *(const s16x8*)(lds8 + (AL) + (MH) * 4096 + mi * 1024 + 8192); }
#define LDB8(BQ, NH, BL) \
  _Pragma("unroll") for (int n2 = 0; n2 < 2; n2++) { \
    BQ[n2][0] = *(const s16x8*)(lds8 + (BL) + ((NH) * 2 + n2) * 1024); \
    BQ[n2][1] = *(const s16x8*)(lds8 + (BL) + ((NH) * 2 + n2) * 1024 + 8192); }
#define MM8(MH, BQ, NH) \
  _Pragma("unroll") for (int mi = 0; mi < 4; mi++) \
  _Pragma("unroll") for (int n2 = 0; n2 < 2; n2++) { \
    acc[(MH)*4+mi][(NH)*2+n2] = __builtin_amdgcn_mfma_f32_16x16x32_bf16( \
        af[mi][0], BQ[n2][0], acc[(MH)*4+mi][(NH)*2+n2], 0, 0, 0); \
    acc[(MH)*4+mi][(NH)*2+n2] = __builtin_amdgcn_mfma_f32_16x16x32_bf16( \
        af[mi][1], BQ[n2][1], acc[(MH)*4+mi][(NH)*2+n2], 0, 0, 0); }
#define BAR() __builtin_amdgcn_s_barrier()
#define LGKM0() asm volatile("s_waitcnt lgkmcnt(0)" ::: "memory")
#define PRIO1() __builtin_amdgcn_s_setprio(1)
#define PRIO0() __builtin_amdgcn_s_setprio(0)

  // prologue: tile0 (buf0) complete + B halves of tile1 (buf1); keep B(1) in flight.
  STG(gB0, stB, 0); STG(gB1, stB + 16384, 0);
  STG(gA0, stA, 0); STG(gA1, stA + 16384, 0);
  STG(gB0, stB + 65536, 1); STG(gB1, stB + 65536 + 16384, 1);
  asm volatile("s_waitcnt vmcnt(4)" ::: "memory");
  BAR();

  for (int it = 0; it < 32; ++it) {
    const int k1 = 2 * it + 1;
    const int k2 = (2 * it + 2 < 64) ? 2 * it + 2 : 63;   // clamped tail stages (never read)
    const int k3 = (2 * it + 3 < 64) ? 2 * it + 3 : 63;
    // ---- K-tile 2it (buf0) ----
    LDA8(0, aL0); LDB8(b0, 0, bL0); STG(gA0, stA + 65536, k1);          // P1
    BAR(); LGKM0(); PRIO1(); MM8(0, b0, 0); PRIO0(); BAR();
    LDB8(b1, 1, bL0); STG(gA1, stA + 65536 + 16384, k1);                 // P2
    BAR(); LGKM0(); PRIO1(); MM8(0, b1, 1); PRIO0(); BAR();
    LDA8(1, aL0); STG(gB0, stB, k2);                                     // P3
    BAR(); LGKM0(); PRIO1(); MM8(1, b1, 1); PRIO0(); BAR();
    STG(gB1, stB + 16384, k2);                                           // P4
    BAR(); PRIO1(); MM8(1, b0, 0); PRIO0();
    asm volatile("s_waitcnt vmcnt(4)" ::: "memory");
    BAR();
    // ---- K-tile 2it+1 (buf1) ----
    LDA8(0, aL1); LDB8(b0, 0, bL1); STG(gA0, stA, k2);                   // P5
    BAR(); LGKM0(); PRIO1(); MM8(0, b0, 0); PRIO0(); BAR();
    LDB8(b1, 1, bL1); STG(gA1, stA + 16384, k2);                         // P6
    BAR(); LGKM0(); PRIO1(); MM8(0, b1, 1); PRIO0(); BAR();
    LDA8(1, aL1); STG(gB0, stB + 65536, k3);                             // P7
    BAR(); LGKM0(); PRIO1(); MM8(1, b1, 1); PRIO0(); BAR();
    STG(gB1, stB + 65536 + 16384, k3);                                   // P8
    BAR(); PRIO1(); MM8(1, b0, 0); PRIO0();
    asm volatile("s_waitcnt vmcnt(4)" ::: "memory");
    BAR();
  }
  asm volatile("s_waitcnt vmcnt(0)" ::: "memory");   // drain before LDS dealloc
  // epilogue: C row = (lane>>4)*4 + rr, col = lane&15 (m89-verified)
#pragma unroll
  for (int mi = 0; mi < 8; mi++)
#pragma unroll
    for (int ni = 0; ni < 4; ni++) {
      const int ml = bm + wm * 128 + mi * 16 + g * 4;
      const int nl = bn + wn * 64 + ni * 16 + l15;
#pragma unroll
      for (int rr = 0; rr < 4; rr++) {
        float v = acc[mi][ni][rr];
        if (QKV)
          Cb[(size_t)(ml + rr) * HID + nl] = f2bf(v * scale);
        else
          Cf[(size_t)(ml + rr) * HID + nl] = v;
      }
    }
#undef STG
#undef LDA8
#undef LDB8
#undef MM8
#undef BAR
#undef LGKM0
#undef PRIO1
#undef PRIO0
}

// ---------------- interleaved RoPE on first 64 chans of each head ----------------
__global__ __launch_bounds__(256) void k_rope(u16* __restrict__ Q, u16* __restrict__ K,
                                              const int* __restrict__ pid) {
  int i = blockIdx.x * 256 + threadIdx.x;   // token*512 + head*32 + pair
  int m = i >> 9, rem = i & 511, h = rem >> 5, p = rem & 31;
  int pos = pid[m];
  double inv = pow(10000.0, -(double)p / 32.0);
  double ang = (double)pos * inv;
  float sv = (float)sin(ang), cv = (float)cos(ang);
  size_t idx = (size_t)m * HID + h * 256 + 2 * p;
  {
    unsigned int qp = *(const unsigned int*)(Q + idx);
    float a = bf2f((u16)qp), b = bf2f((u16)(qp >> 16));
    unsigned int o = (unsigned int)f2bf(a * cv - b * sv) |
                     ((unsigned int)f2bf(b * cv + a * sv) << 16);
    *(unsigned int*)(Q + idx) = o;
  }
  {
    unsigned int kp = *(const unsigned int*)(K + idx);
    float a = bf2f((u16)kp), b = bf2f((u16)(kp >> 16));
    unsigned int o = (unsigned int)f2bf(a * cv - b * sv) |
                     ((unsigned int)f2bf(b * cv + a * sv) << 16);
    *(unsigned int*)(K + idx) = o;
  }
}

// ---------------- flash attention (R2) ----------------
// BQ=64 (4 waves x 16 rows), BK=64, D=256. Grid (32 qt, 32 bh) = 1024 blocks.
__global__ __launch_bounds__(256, 2) void k_flash(const u16* __restrict__ Q,
                                                  const u16* __restrict__ Kg,
                                                  const u16* __restrict__ Vt,
                                                  const float* __restrict__ am,
                                                  u16* __restrict__ O) {
  __shared__ u16 smem[36864];        // 72 KB
  u16* sK = smem;                    // [64 kt][256 d]  swizzled, 32 chunks/row
  u16* sV = smem + 16384;            // [256 d][64 kt]  swizzled, 8 chunks/row
  u16* sP = smem + 32768;            // [64 q][64 kt]   swizzled, 8 chunks/row
  const int t = threadIdx.x, lane = t & 63, w = t >> 6;
  const int qt = gridDim.x - 1 - blockIdx.x;   // longest blocks first
  const int q0 = qt * 64;
  const int bh = blockIdx.y, b = bh >> 4, h = bh & 15;
  const size_t tokb = (size_t)b * SEQ;
  const int ch0 = h * 256;

  // Q tile 64x256 staged once through sK region, then kept in registers
  for (int j = 0; j < 8; j++) {
    int fc = j * 256 + t;
    int r = fc >> 5, cs = fc & 31, cg = cs ^ (r & 7);
    cp16(Q + (tokb + q0 + r) * (size_t)HID + ch0 + cg * 8, sK + j * 2048 + w * 512);
  }
  __syncthreads();
  s16x8 qf[8];
  {
    int rq = w * 16 + (lane & 15);
    for (int kf = 0; kf < 8; kf++) {
      int cs = ((lane >> 4) + 4 * kf) ^ (rq & 7);
      qf[kf] = *(const s16x8*)(sK + rq * 256 + cs * 8);
    }
  }
  f32x4 oacc[16] = {};
  float mrow[4], lrow[4];
  for (int rr = 0; rr < 4; rr++) { mrow[rr] = -1e30f; lrow[rr] = 0.f; }

  const int ntiles = qt + 1;
  for (int it = 0; it < ntiles; it++) {
    const int kt0 = it * 64;
    __syncthreads();   // prev-iter LDS reads done before restage
    for (int j = 0; j < 8; j++) {
      int fc = j * 256 + t;
      int r = fc >> 5, cs = fc & 31, cg = cs ^ (r & 7);
      cp16(Kg + (tokb + kt0 + r) * (size_t)HID + ch0 + cg * 8, sK + j * 2048 + w * 512);
    }
    for (int j = 0; j < 8; j++) {
      int fc = j * 256 + t;
      int rd = fc >> 3, cs = fc & 7, cg = cs ^ (rd & 7);
      cp16(Vt + ((size_t)bh * 256 + rd) * SEQ + kt0 + cg * 8, sV + j * 2048 + w * 512);
    }
    __syncthreads();
    // S = Q K^T  (M=16/wave, N=64, K=256)
    f32x4 sacc[4] = {};
    for (int kf = 0; kf < 8; kf++) {
      s16x8 bf[4];
      for (int ni = 0; ni < 4; ni++) {
        int rk = ni * 16 + (lane & 15);
        int cs = ((lane >> 4) + 4 * kf) ^ (rk & 7);
        bf[ni] = *(const s16x8*)(sK + rk * 256 + cs * 8);
      }
      for (int ni = 0; ni < 4; ni++)
        sacc[ni] = __builtin_amdgcn_mfma_f32_16x16x32_bf16(qf[kf], bf[ni], sacc[ni], 0, 0, 0);
    }
    // masks (pad + causal on diagonal tile only)
    float amv[4];
    for (int ni = 0; ni < 4; ni++) amv[ni] = am[b * SEQ + kt0 + ni * 16 + (lane & 15)];
    const bool tail = (kt0 + 64 > q0);
    {
      int rbase = q0 + w * 16 + ((lane >> 4) << 2);
      for (int ni = 0; ni < 4; ni++) {
        int colg = kt0 + ni * 16 + (lane & 15);
        bool dead = (amv[ni] <= 0.f);
        for (int rr = 0; rr < 4; rr++)
          if (dead || (tail && colg > rbase + rr)) sacc[ni][rr] = -1e30f;
      }
    }
    // online softmax (rows live in 16-lane groups; xor-shuffle 1,2,4,8)
    float alpha[4];
    for (int rr = 0; rr < 4; rr++) {
      float v = fmaxf(fmaxf(sacc[0][rr], sacc[1][rr]),
                      fmaxf(sacc[2][rr], sacc[3][rr]));
      v = fmaxf(v, __shfl_xor(v, 1));
      v = fmaxf(v, __shfl_xor(v, 2));
      v = fmaxf(v, __shfl_xor(v, 4));
      v = fmaxf(v, __shfl_xor(v, 8));
      float mnew = fmaxf(mrow[rr], v);
      alpha[rr] = __expf(mrow[rr] - mnew);
      mrow[rr] = mnew;
    }
    for (int ni = 0; ni < 4; ni++)
      for (int rr = 0; rr < 4; rr++)
        sacc[ni][rr] = __expf(sacc[ni][rr] - mrow[rr]);
    for (int rr = 0; rr < 4; rr++) {
      float sm = sacc[0][rr] + sacc[1][rr] + sacc[2][rr] + sacc[3][rr];
      sm += __shfl_xor(sm, 1);
      sm += __shfl_xor(sm, 2);
      sm += __shfl_xor(sm, 4);
      sm += __shfl_xor(sm, 8);
      lrow[rr] = lrow[rr] * alpha[rr] + sm;
    }
    for (int nd = 0; nd < 16; nd++)
      for (int rr = 0; rr < 4; rr++) oacc[nd][rr] *= alpha[rr];
    // P -> LDS (C-layout -> A-layout, wave-private rows; no barrier needed)
    for (int ni = 0; ni < 4; ni++) {
      int ktl = ni * 16 + (lane & 15);
      for (int rr = 0; rr < 4; rr++) {
        int pq = w * 16 + ((lane >> 4) << 2) + rr;
        int cs = (ktl >> 3) ^ (pq & 7);
        sP[pq * 64 + cs * 8 + (ktl & 7)] = f2bf(sacc[ni][rr]);
      }
    }
    // O += P V   (N=256, K=64)
    for (int kf2 = 0; kf2 < 2; kf2++) {
      s16x8 pa;
      {
        int pq = w * 16 + (lane & 15);
        int cs = ((lane >> 4) + 4 * kf2) ^ (pq & 7);
        pa = *(const s16x8*)(sP + pq * 64 + cs * 8);
      }
      for (int nd = 0; nd < 16; nd++) {
        int rd = nd * 16 + (lane & 15);
        int cs = ((lane >> 4) + 4 * kf2) ^ (rd & 7);
        s16x8 vb = *(const s16x8*)(sV + rd * 64 + cs * 8);
        oacc[nd] = __builtin_amdgcn_mfma_f32_16x16x32_bf16(pa, vb, oacc[nd], 0, 0, 0);
      }
    }
  }
  // epilogue: O / l -> bf16
  {
    float rl[4];
    for (int rr = 0; rr < 4; rr++) rl[rr] = (lrow[rr] > 0.f) ? 1.f / lrow[rr] : 0.f;
    for (int nd = 0; nd < 16; nd++)
      for (int rr = 0; rr < 4; rr++) {
        size_t row = tokb + q0 + w * 16 + ((lane >> 4) << 2) + rr;
        O[row * HID + ch0 + nd * 16 + (lane & 15)] = f2bf(oacc[nd][rr] * rl[rr]);
      }
  }
}

extern "C" void kernel_launch(void* const* d_in, const int* in_sizes, int n_in,
                              void* d_out, int out_size, void* d_ws, size_t ws_size,
                              hipStream_t stream) {
  const float* hs = (const float*)d_in[0];
  const float* am = (const float*)d_in[1];
  const int* pid = (const int*)d_in[2];
  const float* Wq = (const float*)d_in[3];
  const float* Wk = (const float*)d_in[4];
  const float* Wv = (const float*)d_in[5];
  const float* Wo = (const float*)d_in[6];
  float* out = (float*)d_out;

  u16* wsp = (u16*)d_ws;
  u16* hsb = wsp;                 // slot 0 (later: attn_out)
  u16* WT = wsp + NMAT;           // slots 1..4: WqT WkT WvT WoT
  u16* Qb = wsp + 5 * NMAT;
  u16* Kb = wsp + 6 * NMAT;
  u16* Vb = wsp + 7 * NMAT;
  u16* Vt = wsp + 1 * NMAT;       // reuse WqT after QKV GEMM
  u16* attn = hsb;                // reuse hs_bf16 after QKV GEMM

  k_cvt<<<8192, 256, 0, stream>>>(hs, hsb);
  k_wtrans<<<dim3(64, 64, 4), 256, 0, stream>>>(Wq, Wk, Wv, Wo, WT);
  k_gemm8<true><<<dim3(16, 16, 3), 512, 0, stream>>>(hsb, WT, Qb, nullptr);
  k_rope<<<8192, 256, 0, stream>>>(Qb, Kb, pid);
  k_vtrans<<<dim3(32, 4, 32), 256, 0, stream>>>(Vb, Vt);
  k_flash<<<dim3(32, 32), 256, 0, stream>>>(Qb, Kb, Vt, am, attn);
  k_gemm8<false><<<dim3(16, 16, 1), 512, 0, stream>>>(attn, WT + 3 * NMAT, nullptr, out);
}